// Round 6
// baseline (185.785 us; speedup 1.0000x reference)
//
#include <hip/hip_runtime.h>

// GATConv single layer. N=50000, E=800000 (+N self loops), IN=128, H*C=128.
//
// R6: GEMM overlapped with the CSR scatter (both independent); bsum-scan
// folded into scatter blocks; agg with 8 edges in flight.
// Pipeline (all on `stream`):
//   memset deg
//   K1 hist_castw : ppos[e] = deg[dst]++ ; low blocks also W -> Wt bf16
//   K2 scan_blocks: per-1024-block exclusive scan of (deg+1) -> partial, bsum
//   K3 gemm_scatter: blocks[0,512)  h_bf16 = x@W via mfma_f32_16x16x32_bf16
//                    (A converted fp32->bf16 in-register; fused a_src/a_dst
//                    epilogue). blocks[512,1024): wave-scan bsum into LDS,
//                    then csr_src[partial[d]+sb[d>>10]+1+ppos[e]] = src and
//                    node-domain row_st finalize + self-loop plant.
//   K4 gat_agg    : wave per dst node; 64-edge coalesced batches; one lane
//                   per edge computes all 4 head weights (4 exp) into LDS;
//                   eight 8-lane groups process 8 edges in flight, 16 ch/lane
//                   (2x uint4); denom in-register; fused /denom+bias stores.
// No segment-max: logits are O(7), exp() safe in fp32; exp(e)/sum == softmax.

constexpr int N_NODES = 50000;
constexpr int N_EDGES = 800000;
constexpr int E_TOT   = N_EDGES + N_NODES;  // 850000
constexpr int HC      = 128;
constexpr float NEG_SLOPE = 0.2f;
constexpr int M_TILES = N_NODES / 16;               // 3125
constexpr int NB_GEMM = 512;
constexpr int NB_SCAT = 512;
constexpr int SCAN_BLOCKS = (N_NODES + 1023) / 1024;  // 49

typedef short short8 __attribute__((ext_vector_type(8)));
typedef float f32x4  __attribute__((ext_vector_type(4)));

__device__ inline unsigned short f2bf(float f) {   // RTNE
    unsigned int u = __float_as_uint(f);
    u += 0x7FFF + ((u >> 16) & 1);
    return (unsigned short)(u >> 16);
}

// ---- K1: edge histogram (+ W transpose/cast piggybacked) ----

__global__ __launch_bounds__(256) void hist_castw(
    const int* __restrict__ edst, int* __restrict__ deg, int* __restrict__ ppos,
    const float* __restrict__ W, unsigned short* __restrict__ wtb)
{
    const int e = blockIdx.x * 256 + threadIdx.x;   // grid covers E exactly
    ppos[e] = atomicAdd(&deg[edst[e]], 1);
    if (e < 128 * 128) {                            // i = n*128 + k
        const int n = e >> 7, k = e & 127;
        wtb[e] = f2bf(W[k * 128 + n]);              // Wt[n][k] = W[k][n]
    }
}

// ---- K2: per-block exclusive scan of (deg+1) ----

__global__ __launch_bounds__(1024) void scan_blocks(const int* __restrict__ deg,
                                                    int* __restrict__ partial,
                                                    int* __restrict__ bsum) {
    __shared__ int sm[1024];
    const int tid = threadIdx.x;
    const int i = blockIdx.x * 1024 + tid;
    const int v = (i < N_NODES) ? deg[i] + 1 : 0;    // +1 = self loop
    sm[tid] = v; __syncthreads();
    for (int off = 1; off < 1024; off <<= 1) {
        const int t = (tid >= off) ? sm[tid - off] : 0;
        __syncthreads();
        sm[tid] += t;
        __syncthreads();
    }
    if (i < N_NODES) partial[i] = sm[tid] - v;
    if (tid == 1023) bsum[blockIdx.x] = sm[1023];
}

// ---- K3: MFMA GEMM (+att-dot epilogue) overlapped with CSR scatter ----

__global__ __launch_bounds__(256) void gemm_scatter(
    const float* __restrict__ x,             // [N,128] fp32
    const unsigned short* __restrict__ wtb,  // [n:128][k:128] bf16
    const float* __restrict__ att_src, const float* __restrict__ att_dst,
    const int* __restrict__ esrc, const int* __restrict__ edst,
    const int* __restrict__ partial, const int* __restrict__ bsum,
    const int* __restrict__ ppos,
    int* __restrict__ row_st, int* __restrict__ csr_src,
    unsigned short* __restrict__ hb,         // [N,128] bf16
    float* __restrict__ a_src, float* __restrict__ a_dst)
{
    if (blockIdx.x >= NB_GEMM) {
        // ---------------- scatter part ----------------
        __shared__ int sb[64];
        if (threadIdx.x < 64) {              // wave 0: exclusive scan of bsum
            const int v = (threadIdx.x < SCAN_BLOCKS) ? bsum[threadIdx.x] : 0;
            int s = v;
            #pragma unroll
            for (int off = 1; off < 64; off <<= 1) {
                const int t = __shfl_up(s, off);
                if ((int)threadIdx.x >= off) s += t;
            }
            sb[threadIdx.x] = s - v;
        }
        __syncthreads();
        for (int idx = (blockIdx.x - NB_GEMM) * 256 + threadIdx.x; idx < E_TOT;
             idx += NB_SCAT * 256) {
            if (idx < N_EDGES) {
                const int d = edst[idx];
                csr_src[partial[d] + sb[d >> 10] + 1 + ppos[idx]] = esrc[idx];
            } else {
                const int i = idx - N_EDGES;             // node domain
                const int r = partial[i] + sb[i >> 10];
                row_st[i] = r;
                csr_src[r] = i;                          // self loop in slot 0
                if (i == 0) row_st[N_NODES] = E_TOT;
            }
        }
        return;
    }
    // ---------------- GEMM part ----------------
    const int wave = threadIdx.x >> 6;
    const int lane = threadIdx.x & 63;
    const int n0   = (wave & 1) * 64;        // n-strip per wave
    const int l15  = lane & 15;
    const int quad = lane >> 4;

    // B frags from pre-cast wtb: B[k=ks*32+quad*8+j][n=n0+16t+l15] = Wt[n][k]
    short8 bfrag[4][4];
    #pragma unroll
    for (int t = 0; t < 4; ++t)
        #pragma unroll
        for (int ks = 0; ks < 4; ++ks)
            bfrag[t][ks] = *(const short8*)&wtb[(n0 + t * 16 + l15) * 128 + ks * 32 + quad * 8];

    float asw[4], adw[4];                    // att weights, col = n0+t*16+l15
    #pragma unroll
    for (int t = 0; t < 4; ++t) {
        asw[t] = att_src[n0 + t * 16 + l15];
        adw[t] = att_dst[n0 + t * 16 + l15];
    }

    for (int mt = blockIdx.x * 2 + (wave >> 1); mt < M_TILES; mt += NB_GEMM * 2) {
        const int m0 = mt * 16;
        short8 afrag[4];                     // A[m=m0+l15][k=ks*32+quad*8+j]
        #pragma unroll
        for (int ks = 0; ks < 4; ++ks) {
            const float4 u0 = *(const float4*)&x[(size_t)(m0 + l15) * 128 + ks * 32 + quad * 8];
            const float4 u1 = *(const float4*)&x[(size_t)(m0 + l15) * 128 + ks * 32 + quad * 8 + 4];
            short8 a;
            a[0] = (short)f2bf(u0.x); a[1] = (short)f2bf(u0.y);
            a[2] = (short)f2bf(u0.z); a[3] = (short)f2bf(u0.w);
            a[4] = (short)f2bf(u1.x); a[5] = (short)f2bf(u1.y);
            a[6] = (short)f2bf(u1.z); a[7] = (short)f2bf(u1.w);
            afrag[ks] = a;
        }

        f32x4 acc[4];
        #pragma unroll
        for (int t = 0; t < 4; ++t) acc[t] = (f32x4){0.f, 0.f, 0.f, 0.f};

        #pragma unroll
        for (int ks = 0; ks < 4; ++ks)
            #pragma unroll
            for (int t = 0; t < 4; ++t)
                acc[t] = __builtin_amdgcn_mfma_f32_16x16x32_bf16(afrag[ks], bfrag[t][ks], acc[t], 0, 0, 0);

        // C/D: row = m0 + quad*4 + r, col = n0 + t*16 + l15
        #pragma unroll
        for (int t = 0; t < 4; ++t)
            #pragma unroll
            for (int r = 0; r < 4; ++r)
                hb[(m0 + quad * 4 + r) * 128 + n0 + t * 16 + l15] = f2bf(acc[t][r]);

        // fused attention dots: per lane, head g = n0/32 + (t>>1)
        float hs[2][4] = {{0.f,0.f,0.f,0.f},{0.f,0.f,0.f,0.f}};
        float hd[2][4] = {{0.f,0.f,0.f,0.f},{0.f,0.f,0.f,0.f}};
        #pragma unroll
        for (int t = 0; t < 4; ++t)
            #pragma unroll
            for (int r = 0; r < 4; ++r) {
                hs[t >> 1][r] += acc[t][r] * asw[t];
                hd[t >> 1][r] += acc[t][r] * adw[t];
            }
        #pragma unroll
        for (int off = 1; off < 16; off <<= 1)
            #pragma unroll
            for (int g = 0; g < 2; ++g)
                #pragma unroll
                for (int r = 0; r < 4; ++r) {
                    hs[g][r] += __shfl_xor(hs[g][r], off);
                    hd[g][r] += __shfl_xor(hd[g][r], off);
                }
        if (l15 == 0) {
            const int hb0 = n0 >> 5;         // first head of this strip
            #pragma unroll
            for (int g = 0; g < 2; ++g)
                #pragma unroll
                for (int r = 0; r < 4; ++r) {
                    a_src[(m0 + quad * 4 + r) * 4 + hb0 + g] = hs[g][r];
                    a_dst[(m0 + quad * 4 + r) * 4 + hb0 + g] = hd[g][r];
                }
        }
    }
}

// ---- K4: aggregation — wave per dst node, 8 edges in flight ----

__global__ __launch_bounds__(256) void gat_agg(
    const int* __restrict__ row_start, const int* __restrict__ csr_src,
    const unsigned short* __restrict__ hb, const float* __restrict__ a_src,
    const float* __restrict__ a_dst, const float* __restrict__ bias,
    float* __restrict__ out)
{
    __shared__ float ws[4][256];             // [wave][edge*4 + head]
    const int wv = threadIdx.x >> 6;
    const int node = blockIdx.x * 4 + wv;
    if (node >= N_NODES) return;
    const int lane = threadIdx.x & 63;
    const int oct  = lane >> 3;              // which of 8 edges in flight
    const int li   = lane & 7;
    const int ch0  = li * 16;                // 16 channels per lane
    const int hd   = li >> 1;                // head of my channels (ch0/32)
    const float4 ad4 = *(const float4*)&a_dst[node * 4];
    const int p0 = row_start[node], p1 = row_start[node + 1];

    float acc[16];
    #pragma unroll
    for (int r = 0; r < 16; ++r) acc[r] = 0.f;
    float dsum = 0.f;

    for (int base = p0; base < p1; base += 64) {
        int m = p1 - base; if (m > 64) m = 64;
        int sv = 0;
        if (lane < m) {
            sv = csr_src[base + lane];       // coalesced batch of src ids
            const float4 av = *(const float4*)&a_src[sv * 4];
            float t; float4 w4;
            t = av.x + ad4.x; t = t > 0.f ? t : NEG_SLOPE * t; w4.x = __expf(t);
            t = av.y + ad4.y; t = t > 0.f ? t : NEG_SLOPE * t; w4.y = __expf(t);
            t = av.z + ad4.z; t = t > 0.f ? t : NEG_SLOPE * t; w4.z = __expf(t);
            t = av.w + ad4.w; t = t > 0.f ? t : NEG_SLOPE * t; w4.w = __expf(t);
            *(float4*)&ws[wv][lane * 4] = w4; // all 4 head weights for my edge
        }
        // same-wave LDS RAW: lockstep + compiler lgkmcnt, no barrier needed
        for (int j = 0; j < m; j += 8) {
            const int ei  = j + oct;         // my edge of the 8 in flight
            const int idx = ei < m ? ei : j;
            const int s   = __shfl(sv, idx);
            float w = ws[wv][idx * 4 + hd];
            if (ei >= m) w = 0.f;
            const uint4 h0 = *(const uint4*)&hb[(size_t)s * 128 + ch0];
            const uint4 h1 = *(const uint4*)&hb[(size_t)s * 128 + ch0 + 8];
            acc[0]  += w * __uint_as_float(h0.x << 16);
            acc[1]  += w * __uint_as_float(h0.x & 0xFFFF0000u);
            acc[2]  += w * __uint_as_float(h0.y << 16);
            acc[3]  += w * __uint_as_float(h0.y & 0xFFFF0000u);
            acc[4]  += w * __uint_as_float(h0.z << 16);
            acc[5]  += w * __uint_as_float(h0.z & 0xFFFF0000u);
            acc[6]  += w * __uint_as_float(h0.w << 16);
            acc[7]  += w * __uint_as_float(h0.w & 0xFFFF0000u);
            acc[8]  += w * __uint_as_float(h1.x << 16);
            acc[9]  += w * __uint_as_float(h1.x & 0xFFFF0000u);
            acc[10] += w * __uint_as_float(h1.y << 16);
            acc[11] += w * __uint_as_float(h1.y & 0xFFFF0000u);
            acc[12] += w * __uint_as_float(h1.z << 16);
            acc[13] += w * __uint_as_float(h1.z & 0xFFFF0000u);
            acc[14] += w * __uint_as_float(h1.w << 16);
            acc[15] += w * __uint_as_float(h1.w & 0xFFFF0000u);
            dsum += w;
        }
    }
    // combine the eight octs (disjoint edge subsets, same channels)
    #pragma unroll
    for (int off = 8; off <= 32; off <<= 1) {
        #pragma unroll
        for (int r = 0; r < 16; ++r) acc[r] += __shfl_xor(acc[r], off);
        dsum += __shfl_xor(dsum, off);
    }
    if (oct == 0) {
        const float inv = 1.f / dsum;        // dsum >= exp(self) > 0
        #pragma unroll
        for (int v = 0; v < 4; ++v) {
            const float4 b4 = *(const float4*)&bias[ch0 + v * 4];
            float4 o;
            o.x = acc[v*4+0]*inv + b4.x; o.y = acc[v*4+1]*inv + b4.y;
            o.z = acc[v*4+2]*inv + b4.z; o.w = acc[v*4+3]*inv + b4.w;
            *(float4*)&out[(size_t)node * HC + ch0 + v * 4] = o;
        }
    }
}

extern "C" void kernel_launch(void* const* d_in, const int* in_sizes, int n_in,
                              void* d_out, int out_size, void* d_ws, size_t ws_size,
                              hipStream_t stream) {
    const float* x       = (const float*)d_in[0];
    const int*   ei      = (const int*)  d_in[1];   // [2,E]: row0=src, row1=dst
    const float* W       = (const float*)d_in[2];
    const float* att_src = (const float*)d_in[3];
    const float* att_dst = (const float*)d_in[4];
    const float* bias    = (const float*)d_in[5];
    float* out = (float*)d_out;

    // ws layout (~21.7 MB): hb | wtb | a_src | a_dst | csr_src | partial | row_st | deg | ppos | bsum
    char* p = (char*)d_ws;
    unsigned short* hb  = (unsigned short*)p; p += (size_t)N_NODES * HC * 2;  // 12.8 MB
    unsigned short* wtb = (unsigned short*)p; p += 128 * 128 * 2;             // 32 KB
    float* a_src = (float*)p; p += (size_t)N_NODES * 4 * 4;                   // 800 KB
    float* a_dst = (float*)p; p += (size_t)N_NODES * 4 * 4;
    int* csr_src = (int*)p;   p += (size_t)E_TOT * 4;                         // 3.4 MB
    int* partial = (int*)p;   p += N_NODES * 4;
    int* row_st  = (int*)p;   p += (N_NODES + 4) * 4;
    int* deg     = (int*)p;   p += N_NODES * 4;
    int* ppos    = (int*)p;   p += (size_t)N_EDGES * 4;                       // 3.2 MB
    int* bsum    = (int*)p;

    const int* esrc = ei;
    const int* edst = ei + N_EDGES;

    hipMemsetAsync(deg, 0, (size_t)N_NODES * sizeof(int), stream);

    hist_castw  <<<N_EDGES / 256, 256, 0, stream>>>(edst, deg, ppos, W, wtb);
    scan_blocks <<<SCAN_BLOCKS, 1024, 0, stream>>>(deg, partial, bsum);
    gemm_scatter<<<NB_GEMM + NB_SCAT, 256, 0, stream>>>(x, wtb, att_src, att_dst,
                                                        esrc, edst, partial, bsum, ppos,
                                                        row_st, csr_src, hb, a_src, a_dst);
    gat_agg     <<<(N_NODES + 3) / 4, 256, 0, stream>>>(row_st, csr_src, hb, a_src,
                                                        a_dst, bias, out);
}

// Round 7
// 183.002 us; speedup vs baseline: 1.0152x; 1.0152x over previous
//
#include <hip/hip_runtime.h>

// GATConv single layer. N=50000, E=800000 (+N self loops), IN=128, H*C=128.
//
// R7: gemm tiles split across ALL three CSR-build stages so every serial
// stage is hidden behind independent MFMA work; agg reverted to proven
// 4-edges-in-flight (R5); csr/ppos as uint16; shfl-based scan.
// Pipeline (all on `stream`):
//   memset deg
//   K1 hist_gemm   : blocks[0,512): ppos[e]=deg[dst]++ (grid-stride).
//                    blocks[512,1024): gemm tiles [0,1024).
//   K2 scan_gemm   : blocks[0,49): 1024-elem exclusive scan of (deg+1) via
//                    shfl (4 elems/thread). blocks[49,305): tiles [1024,1536).
//   K3 scatter_gemm: blocks[0,512): wave-scan bsum in LDS, then
//                    csr[partial[d]+sb+1+ppos[e]]=src + row_st finalize +
//                    self-loop plant. blocks[512,1307): tiles [1536,3125).
//   K4 gat_agg     : wave per dst node; 64-edge coalesced batches; one lane
//                    per edge computes 4 head weights into LDS; four
//                    quarter-waves process 4 edges in flight, 8 ch/lane.
// No segment-max: logits are O(7), exp() safe in fp32; exp(e)/sum == softmax.

constexpr int N_NODES = 50000;
constexpr int N_EDGES = 800000;
constexpr int E_TOT   = N_EDGES + N_NODES;  // 850000
constexpr int HC      = 128;
constexpr float NEG_SLOPE = 0.2f;
constexpr int M_TILES = N_NODES / 16;               // 3125
constexpr int SCAN_BLOCKS = (N_NODES + 1023) / 1024;  // 49

// gemm tile ranges per stage
constexpr int TA_LO = 0,    TA_HI = 1024;
constexpr int TB_LO = 1024, TB_HI = 1536;
constexpr int TC_LO = 1536, TC_HI = M_TILES;        // 1589 tiles
constexpr int NB_HIST = 512, NB_GA = 512;           // K1: 1024 blocks
constexpr int NB_GB = 256;                          // K2: 49+256 blocks
constexpr int NB_SCAT = 512, NB_GC = 795;           // K3: 1307 blocks

typedef short short8 __attribute__((ext_vector_type(8)));
typedef float f32x4  __attribute__((ext_vector_type(4)));

__device__ inline unsigned short f2bf(float f) {   // RTNE
    unsigned int u = __float_as_uint(f);
    u += 0x7FFF + ((u >> 16) & 1);
    return (unsigned short)(u >> 16);
}

// ---- shared gemm worker: tiles [lo + gb*2 + (wave>>1)] , h=x@W + att dots ----

__device__ __forceinline__ void gemm_tiles(
    int gb, int lo, int hi,
    const float* __restrict__ x, const float* __restrict__ W,
    const float* __restrict__ att_src, const float* __restrict__ att_dst,
    unsigned short* __restrict__ hb,
    float* __restrict__ a_src, float* __restrict__ a_dst)
{
    const int wave = threadIdx.x >> 6;
    const int lane = threadIdx.x & 63;
    const int n0   = (wave & 1) * 64;        // n-strip per wave
    const int l15  = lane & 15;
    const int quad = lane >> 4;
    const int mt   = lo + gb * 2 + (wave >> 1);
    if (mt >= hi) return;

    // B frags direct from fp32 W (64 KB, L2-hot):
    // B[k=ks*32+quad*8+j][n=n0+16t+l15] = W[k*128+n]
    short8 bfrag[4][4];
    #pragma unroll
    for (int t = 0; t < 4; ++t)
        #pragma unroll
        for (int ks = 0; ks < 4; ++ks) {
            short8 b;
            #pragma unroll
            for (int j = 0; j < 8; ++j)
                b[j] = (short)f2bf(W[(ks * 32 + quad * 8 + j) * 128 + n0 + t * 16 + l15]);
            bfrag[t][ks] = b;
        }

    float asw[4], adw[4];                    // att weights, col = n0+t*16+l15
    #pragma unroll
    for (int t = 0; t < 4; ++t) {
        asw[t] = att_src[n0 + t * 16 + l15];
        adw[t] = att_dst[n0 + t * 16 + l15];
    }

    const int m0 = mt * 16;
    short8 afrag[4];                         // A[m=m0+l15][k=ks*32+quad*8+j]
    #pragma unroll
    for (int ks = 0; ks < 4; ++ks) {
        const float4 u0 = *(const float4*)&x[(size_t)(m0 + l15) * 128 + ks * 32 + quad * 8];
        const float4 u1 = *(const float4*)&x[(size_t)(m0 + l15) * 128 + ks * 32 + quad * 8 + 4];
        short8 a;
        a[0] = (short)f2bf(u0.x); a[1] = (short)f2bf(u0.y);
        a[2] = (short)f2bf(u0.z); a[3] = (short)f2bf(u0.w);
        a[4] = (short)f2bf(u1.x); a[5] = (short)f2bf(u1.y);
        a[6] = (short)f2bf(u1.z); a[7] = (short)f2bf(u1.w);
        afrag[ks] = a;
    }

    f32x4 acc[4];
    #pragma unroll
    for (int t = 0; t < 4; ++t) acc[t] = (f32x4){0.f, 0.f, 0.f, 0.f};

    #pragma unroll
    for (int ks = 0; ks < 4; ++ks)
        #pragma unroll
        for (int t = 0; t < 4; ++t)
            acc[t] = __builtin_amdgcn_mfma_f32_16x16x32_bf16(afrag[ks], bfrag[t][ks], acc[t], 0, 0, 0);

    // C/D: row = m0 + quad*4 + r, col = n0 + t*16 + l15
    #pragma unroll
    for (int t = 0; t < 4; ++t)
        #pragma unroll
        for (int r = 0; r < 4; ++r)
            hb[(m0 + quad * 4 + r) * 128 + n0 + t * 16 + l15] = f2bf(acc[t][r]);

    // fused attention dots: per lane, head g = n0/32 + (t>>1)
    float hs[2][4] = {{0.f,0.f,0.f,0.f},{0.f,0.f,0.f,0.f}};
    float hd[2][4] = {{0.f,0.f,0.f,0.f},{0.f,0.f,0.f,0.f}};
    #pragma unroll
    for (int t = 0; t < 4; ++t)
        #pragma unroll
        for (int r = 0; r < 4; ++r) {
            hs[t >> 1][r] += acc[t][r] * asw[t];
            hd[t >> 1][r] += acc[t][r] * adw[t];
        }
    #pragma unroll
    for (int off = 1; off < 16; off <<= 1)
        #pragma unroll
        for (int g = 0; g < 2; ++g)
            #pragma unroll
            for (int r = 0; r < 4; ++r) {
                hs[g][r] += __shfl_xor(hs[g][r], off);
                hd[g][r] += __shfl_xor(hd[g][r], off);
            }
    if (l15 == 0) {
        const int hb0 = n0 >> 5;             // first head of this strip
        #pragma unroll
        for (int g = 0; g < 2; ++g)
            #pragma unroll
            for (int r = 0; r < 4; ++r) {
                a_src[(m0 + quad * 4 + r) * 4 + hb0 + g] = hs[g][r];
                a_dst[(m0 + quad * 4 + r) * 4 + hb0 + g] = hd[g][r];
            }
    }
}

// ---- K1: edge histogram (low blocks) ∥ gemm tiles A (high blocks) ----

__global__ __launch_bounds__(256) void hist_gemm(
    const int* __restrict__ edst, int* __restrict__ deg,
    unsigned short* __restrict__ ppos,
    const float* __restrict__ x, const float* __restrict__ W,
    const float* __restrict__ att_src, const float* __restrict__ att_dst,
    unsigned short* __restrict__ hb,
    float* __restrict__ a_src, float* __restrict__ a_dst)
{
    if (blockIdx.x < NB_HIST) {
        for (int e = blockIdx.x * 256 + threadIdx.x; e < N_EDGES; e += NB_HIST * 256)
            ppos[e] = (unsigned short)atomicAdd(&deg[edst[e]], 1);
        return;
    }
    gemm_tiles(blockIdx.x - NB_HIST, TA_LO, TA_HI, x, W, att_src, att_dst, hb, a_src, a_dst);
}

// ---- K2: shfl-based exclusive scan of (deg+1) ∥ gemm tiles B ----

__global__ __launch_bounds__(256) void scan_gemm(
    const int* __restrict__ deg, int* __restrict__ partial, int* __restrict__ bsum,
    const float* __restrict__ x, const float* __restrict__ W,
    const float* __restrict__ att_src, const float* __restrict__ att_dst,
    unsigned short* __restrict__ hb,
    float* __restrict__ a_src, float* __restrict__ a_dst)
{
    if (blockIdx.x < SCAN_BLOCKS) {
        __shared__ int wsum[4];
        const int tid  = threadIdx.x;
        const int lane = tid & 63;
        const int wv   = tid >> 6;
        const int base = blockIdx.x * 1024 + tid * 4;
        int d0 = 0, d1 = 0, d2 = 0, d3 = 0;
        if (base + 3 < N_NODES) {
            const int4 v = *(const int4*)&deg[base];
            d0 = v.x + 1; d1 = v.y + 1; d2 = v.z + 1; d3 = v.w + 1;
        } else {
            if (base + 0 < N_NODES) d0 = deg[base + 0] + 1;
            if (base + 1 < N_NODES) d1 = deg[base + 1] + 1;
            if (base + 2 < N_NODES) d2 = deg[base + 2] + 1;
            if (base + 3 < N_NODES) d3 = deg[base + 3] + 1;
        }
        const int s0 = d0, s1 = s0 + d1, s2 = s1 + d2, s3 = s2 + d3;
        int inc = s3;                        // wave-inclusive scan of totals
        #pragma unroll
        for (int off = 1; off < 64; off <<= 1) {
            const int t = __shfl_up(inc, off);
            if (lane >= off) inc += t;
        }
        if (lane == 63) wsum[wv] = inc;
        __syncthreads();
        int wbase = 0;
        for (int k = 0; k < wv; ++k) wbase += wsum[k];
        const int tb = wbase + inc - s3;     // exclusive base for this thread
        if (base + 3 < N_NODES) {
            *(int4*)&partial[base] = (int4){tb, tb + s0, tb + s1, tb + s2};
        } else {
            if (base + 0 < N_NODES) partial[base + 0] = tb;
            if (base + 1 < N_NODES) partial[base + 1] = tb + s0;
            if (base + 2 < N_NODES) partial[base + 2] = tb + s1;
            if (base + 3 < N_NODES) partial[base + 3] = tb + s2;
        }
        if (tid == 255) bsum[blockIdx.x] = wbase + inc;
        return;
    }
    gemm_tiles(blockIdx.x - SCAN_BLOCKS, TB_LO, TB_HI, x, W, att_src, att_dst, hb, a_src, a_dst);
}

// ---- K3: CSR scatter + row_st finalize (low blocks) ∥ gemm tiles C ----

__global__ __launch_bounds__(256) void scatter_gemm(
    const int* __restrict__ esrc, const int* __restrict__ edst,
    const int* __restrict__ partial, const int* __restrict__ bsum,
    const unsigned short* __restrict__ ppos,
    int* __restrict__ row_st, unsigned short* __restrict__ csr_src,
    const float* __restrict__ x, const float* __restrict__ W,
    const float* __restrict__ att_src, const float* __restrict__ att_dst,
    unsigned short* __restrict__ hb,
    float* __restrict__ a_src, float* __restrict__ a_dst)
{
    if (blockIdx.x < NB_SCAT) {
        __shared__ int sb[64];
        if (threadIdx.x < 64) {              // wave 0: exclusive scan of bsum
            const int v = (threadIdx.x < SCAN_BLOCKS) ? bsum[threadIdx.x] : 0;
            int s = v;
            #pragma unroll
            for (int off = 1; off < 64; off <<= 1) {
                const int t = __shfl_up(s, off);
                if ((int)threadIdx.x >= off) s += t;
            }
            sb[threadIdx.x] = s - v;
        }
        __syncthreads();
        for (int idx = blockIdx.x * 256 + threadIdx.x; idx < E_TOT; idx += NB_SCAT * 256) {
            if (idx < N_EDGES) {
                const int d = edst[idx];
                csr_src[partial[d] + sb[d >> 10] + 1 + ppos[idx]] = (unsigned short)esrc[idx];
            } else {
                const int i = idx - N_EDGES;             // node domain
                const int r = partial[i] + sb[i >> 10];
                row_st[i] = r;
                csr_src[r] = (unsigned short)i;          // self loop in slot 0
                if (i == 0) row_st[N_NODES] = E_TOT;
            }
        }
        return;
    }
    gemm_tiles(blockIdx.x - NB_SCAT, TC_LO, TC_HI, x, W, att_src, att_dst, hb, a_src, a_dst);
}

// ---- K4: aggregation — wave per dst node, 4 edges in flight (R5-proven) ----

__global__ __launch_bounds__(256) void gat_agg(
    const int* __restrict__ row_start, const unsigned short* __restrict__ csr_src,
    const unsigned short* __restrict__ hb, const float* __restrict__ a_src,
    const float* __restrict__ a_dst, const float* __restrict__ bias,
    float* __restrict__ out)
{
    __shared__ float ws[4][256];             // [wave][edge*4 + head]
    const int wv = threadIdx.x >> 6;
    const int node = blockIdx.x * 4 + wv;
    if (node >= N_NODES) return;
    const int lane = threadIdx.x & 63;
    const int q    = lane >> 4;              // quarter: which edge of the 4
    const int li   = lane & 15;
    const int ch0  = li * 8;                 // 8 channels per lane
    const int hd   = li >> 2;                // head of my channels (ch0/32)
    const float4 ad4 = *(const float4*)&a_dst[node * 4];
    const int p0 = row_start[node], p1 = row_start[node + 1];

    float acc[8] = {0.f,0.f,0.f,0.f,0.f,0.f,0.f,0.f};
    float dsum = 0.f;

    for (int base = p0; base < p1; base += 64) {
        int m = p1 - base; if (m > 64) m = 64;
        int sv = 0;
        if (lane < m) {
            sv = (int)csr_src[base + lane];  // coalesced batch of src ids
            const float4 av = *(const float4*)&a_src[sv * 4];
            float t; float4 w4;
            t = av.x + ad4.x; t = t > 0.f ? t : NEG_SLOPE * t; w4.x = __expf(t);
            t = av.y + ad4.y; t = t > 0.f ? t : NEG_SLOPE * t; w4.y = __expf(t);
            t = av.z + ad4.z; t = t > 0.f ? t : NEG_SLOPE * t; w4.z = __expf(t);
            t = av.w + ad4.w; t = t > 0.f ? t : NEG_SLOPE * t; w4.w = __expf(t);
            *(float4*)&ws[wv][lane * 4] = w4; // all 4 head weights for my edge
        }
        // same-wave LDS RAW: lockstep + compiler lgkmcnt, no barrier needed
        for (int j = 0; j < m; j += 4) {
            const int ei  = j + q;           // quarter q -> edge j+q
            const int idx = ei < m ? ei : j;
            const int s   = __shfl(sv, idx);
            float w = ws[wv][idx * 4 + hd];
            if (ei >= m) w = 0.f;
            const uint4 hv = *(const uint4*)&hb[(size_t)s * 128 + ch0];
            acc[0] += w * __uint_as_float(hv.x << 16);
            acc[1] += w * __uint_as_float(hv.x & 0xFFFF0000u);
            acc[2] += w * __uint_as_float(hv.y << 16);
            acc[3] += w * __uint_as_float(hv.y & 0xFFFF0000u);
            acc[4] += w * __uint_as_float(hv.z << 16);
            acc[5] += w * __uint_as_float(hv.z & 0xFFFF0000u);
            acc[6] += w * __uint_as_float(hv.w << 16);
            acc[7] += w * __uint_as_float(hv.w & 0xFFFF0000u);
            dsum += w;
        }
    }
    // combine the four quarters (disjoint edge subsets, same channels)
    #pragma unroll
    for (int off = 16; off <= 32; off <<= 1) {
        #pragma unroll
        for (int r = 0; r < 8; ++r) acc[r] += __shfl_xor(acc[r], off);
        dsum += __shfl_xor(dsum, off);
    }
    if (q == 0) {
        const float inv = 1.f / dsum;        // dsum >= exp(self) > 0
        const float4 b0 = *(const float4*)&bias[ch0];
        const float4 b1 = *(const float4*)&bias[ch0 + 4];
        float4 o0, o1;
        o0.x = acc[0]*inv + b0.x; o0.y = acc[1]*inv + b0.y;
        o0.z = acc[2]*inv + b0.z; o0.w = acc[3]*inv + b0.w;
        o1.x = acc[4]*inv + b1.x; o1.y = acc[5]*inv + b1.y;
        o1.z = acc[6]*inv + b1.z; o1.w = acc[7]*inv + b1.w;
        *(float4*)&out[(size_t)node * HC + ch0]     = o0;
        *(float4*)&out[(size_t)node * HC + ch0 + 4] = o1;
    }
}

extern "C" void kernel_launch(void* const* d_in, const int* in_sizes, int n_in,
                              void* d_out, int out_size, void* d_ws, size_t ws_size,
                              hipStream_t stream) {
    const float* x       = (const float*)d_in[0];
    const int*   ei      = (const int*)  d_in[1];   // [2,E]: row0=src, row1=dst
    const float* W       = (const float*)d_in[2];
    const float* att_src = (const float*)d_in[3];
    const float* att_dst = (const float*)d_in[4];
    const float* bias    = (const float*)d_in[5];
    float* out = (float*)d_out;

    // ws layout (~18 MB): hb | a_src | a_dst | csr(u16) | ppos(u16) | partial | row_st | deg | bsum
    char* p = (char*)d_ws;
    unsigned short* hb  = (unsigned short*)p; p += (size_t)N_NODES * HC * 2;  // 12.8 MB
    float* a_src = (float*)p; p += (size_t)N_NODES * 4 * 4;                   // 800 KB
    float* a_dst = (float*)p; p += (size_t)N_NODES * 4 * 4;
    unsigned short* csr_src = (unsigned short*)p; p += (size_t)E_TOT * 2;     // 1.7 MB
    unsigned short* ppos    = (unsigned short*)p; p += (size_t)N_EDGES * 2;   // 1.6 MB
    int* partial = (int*)p;   p += N_NODES * 4;
    int* row_st  = (int*)p;   p += (N_NODES + 4) * 4;
    int* deg     = (int*)p;   p += N_NODES * 4;
    int* bsum    = (int*)p;

    const int* esrc = ei;
    const int* edst = ei + N_EDGES;

    hipMemsetAsync(deg, 0, (size_t)N_NODES * sizeof(int), stream);

    hist_gemm   <<<NB_HIST + NB_GA, 256, 0, stream>>>(edst, deg, ppos,
                                                      x, W, att_src, att_dst, hb, a_src, a_dst);
    scan_gemm   <<<SCAN_BLOCKS + NB_GB, 256, 0, stream>>>(deg, partial, bsum,
                                                      x, W, att_src, att_dst, hb, a_src, a_dst);
    scatter_gemm<<<NB_SCAT + NB_GC, 256, 0, stream>>>(esrc, edst, partial, bsum, ppos,
                                                      row_st, csr_src,
                                                      x, W, att_src, att_dst, hb, a_src, a_dst);
    gat_agg     <<<(N_NODES + 3) / 4, 256, 0, stream>>>(row_st, csr_src, hb, a_src,
                                                        a_dst, bias, out);
}

// Round 8
// 170.663 us; speedup vs baseline: 1.0886x; 1.0723x over previous
//
#include <hip/hip_runtime.h>

// GATConv single layer. N=50000, E=800000 (+N self loops), IN=128, H*C=128.
//
// R8 = R5 skeleton (best measured, 174us) + upgrades:
//   - agg: software-pipelined prefetch (8 h-rows in flight, 4-edge granular)
//   - scan: 1-barrier shfl scan; bsum scan folded into scatter blocks
//   - uint16 csr_src/ppos
// Pipeline (all on `stream`):
//   memset deg
//   K1 gemm_hist  : blocks[0,512) h_bf16=x@W via mfma_f32_16x16x32_bf16
//                   (A and B converted fp32->bf16 in-register; fused
//                   a_src/a_dst epilogue). blocks[512,1024): ppos[e]=deg[d]++.
//   K2 scan       : 49 blocks, 4 elems/thread shfl scan of (deg+1) -> partial,bsum
//   K3 scatter_fin: per-block wave-scan of bsum; edges: csr[...]=src;
//                   nodes: row_st finalize + self-loop plant.
//   K4 gat_agg    : wave per dst node; 64-edge batches; per-edge 4 head
//                   weights into LDS (4 exp/lane); 4 quarter-waves process 4
//                   edges in flight with next-group prefetch; /denom+bias.
// No segment-max: logits are O(7), exp() safe in fp32; exp(e)/sum == softmax.

constexpr int N_NODES = 50000;
constexpr int N_EDGES = 800000;
constexpr int E_TOT   = N_EDGES + N_NODES;  // 850000
constexpr int HC      = 128;
constexpr float NEG_SLOPE = 0.2f;
constexpr int M_TILES = N_NODES / 16;               // 3125
constexpr int NB_GEMM = 512;
constexpr int NB_HIST = 512;
constexpr int SCAN_BLOCKS = (N_NODES + 1023) / 1024;  // 49

typedef short short8 __attribute__((ext_vector_type(8)));
typedef float f32x4  __attribute__((ext_vector_type(4)));

__device__ inline unsigned short f2bf(float f) {   // RTNE
    unsigned int u = __float_as_uint(f);
    u += 0x7FFF + ((u >> 16) & 1);
    return (unsigned short)(u >> 16);
}

// ---- K1: MFMA GEMM (+att-dot epilogue) overlapped with edge histogram ----

__global__ __launch_bounds__(256) void gemm_hist(
    const float* __restrict__ x,             // [N,128] fp32
    const float* __restrict__ W,             // [k:128][n:128] fp32
    const float* __restrict__ att_src, const float* __restrict__ att_dst,
    const int* __restrict__ edst,
    unsigned short* __restrict__ hb,         // [N,128] bf16
    float* __restrict__ a_src, float* __restrict__ a_dst,
    int* __restrict__ deg, unsigned short* __restrict__ ppos)
{
    if (blockIdx.x >= NB_GEMM) {
        // ---------------- histogram part ----------------
        const int t0 = (blockIdx.x - NB_GEMM) * 256 + threadIdx.x;
        for (int e = t0; e < N_EDGES; e += NB_HIST * 256)
            ppos[e] = (unsigned short)atomicAdd(&deg[edst[e]], 1);
        return;
    }
    // ---------------- GEMM part ----------------
    const int wave = threadIdx.x >> 6;
    const int lane = threadIdx.x & 63;
    const int n0   = (wave & 1) * 64;        // n-strip per wave
    const int l15  = lane & 15;
    const int quad = lane >> 4;

    // B frags direct from fp32 W (64 KB, L2-hot; amortized over ~6 tiles):
    // B[k=ks*32+quad*8+j][n=n0+16t+l15] = W[k*128+n]
    short8 bfrag[4][4];
    #pragma unroll
    for (int t = 0; t < 4; ++t)
        #pragma unroll
        for (int ks = 0; ks < 4; ++ks) {
            short8 b;
            #pragma unroll
            for (int j = 0; j < 8; ++j)
                b[j] = (short)f2bf(W[(ks * 32 + quad * 8 + j) * 128 + n0 + t * 16 + l15]);
            bfrag[t][ks] = b;
        }

    float asw[4], adw[4];                    // att weights, col = n0+t*16+l15
    #pragma unroll
    for (int t = 0; t < 4; ++t) {
        asw[t] = att_src[n0 + t * 16 + l15];
        adw[t] = att_dst[n0 + t * 16 + l15];
    }

    for (int mt = blockIdx.x * 2 + (wave >> 1); mt < M_TILES; mt += NB_GEMM * 2) {
        const int m0 = mt * 16;
        short8 afrag[4];                     // A[m=m0+l15][k=ks*32+quad*8+j]
        #pragma unroll
        for (int ks = 0; ks < 4; ++ks) {
            const float4 u0 = *(const float4*)&x[(size_t)(m0 + l15) * 128 + ks * 32 + quad * 8];
            const float4 u1 = *(const float4*)&x[(size_t)(m0 + l15) * 128 + ks * 32 + quad * 8 + 4];
            short8 a;
            a[0] = (short)f2bf(u0.x); a[1] = (short)f2bf(u0.y);
            a[2] = (short)f2bf(u0.z); a[3] = (short)f2bf(u0.w);
            a[4] = (short)f2bf(u1.x); a[5] = (short)f2bf(u1.y);
            a[6] = (short)f2bf(u1.z); a[7] = (short)f2bf(u1.w);
            afrag[ks] = a;
        }

        f32x4 acc[4];
        #pragma unroll
        for (int t = 0; t < 4; ++t) acc[t] = (f32x4){0.f, 0.f, 0.f, 0.f};

        #pragma unroll
        for (int ks = 0; ks < 4; ++ks)
            #pragma unroll
            for (int t = 0; t < 4; ++t)
                acc[t] = __builtin_amdgcn_mfma_f32_16x16x32_bf16(afrag[ks], bfrag[t][ks], acc[t], 0, 0, 0);

        // C/D: row = m0 + quad*4 + r, col = n0 + t*16 + l15
        #pragma unroll
        for (int t = 0; t < 4; ++t)
            #pragma unroll
            for (int r = 0; r < 4; ++r)
                hb[(m0 + quad * 4 + r) * 128 + n0 + t * 16 + l15] = f2bf(acc[t][r]);

        // fused attention dots: per lane, head g = n0/32 + (t>>1)
        float hs[2][4] = {{0.f,0.f,0.f,0.f},{0.f,0.f,0.f,0.f}};
        float hd[2][4] = {{0.f,0.f,0.f,0.f},{0.f,0.f,0.f,0.f}};
        #pragma unroll
        for (int t = 0; t < 4; ++t)
            #pragma unroll
            for (int r = 0; r < 4; ++r) {
                hs[t >> 1][r] += acc[t][r] * asw[t];
                hd[t >> 1][r] += acc[t][r] * adw[t];
            }
        #pragma unroll
        for (int off = 1; off < 16; off <<= 1)
            #pragma unroll
            for (int g = 0; g < 2; ++g)
                #pragma unroll
                for (int r = 0; r < 4; ++r) {
                    hs[g][r] += __shfl_xor(hs[g][r], off);
                    hd[g][r] += __shfl_xor(hd[g][r], off);
                }
        if (l15 == 0) {
            const int hb0 = n0 >> 5;         // first head of this strip
            #pragma unroll
            for (int g = 0; g < 2; ++g)
                #pragma unroll
                for (int r = 0; r < 4; ++r) {
                    a_src[(m0 + quad * 4 + r) * 4 + hb0 + g] = hs[g][r];
                    a_dst[(m0 + quad * 4 + r) * 4 + hb0 + g] = hd[g][r];
                }
        }
    }
}

// ---- K2: 1-barrier shfl exclusive scan of (deg+1), 4 elems/thread ----

__global__ __launch_bounds__(256) void scan(
    const int* __restrict__ deg, int* __restrict__ partial, int* __restrict__ bsum)
{
    __shared__ int wsum[4];
    const int tid  = threadIdx.x;
    const int lane = tid & 63;
    const int wv   = tid >> 6;
    const int base = blockIdx.x * 1024 + tid * 4;
    int d0 = 0, d1 = 0, d2 = 0, d3 = 0;
    if (base + 3 < N_NODES) {
        const int4 v = *(const int4*)&deg[base];
        d0 = v.x + 1; d1 = v.y + 1; d2 = v.z + 1; d3 = v.w + 1;
    } else {
        if (base + 0 < N_NODES) d0 = deg[base + 0] + 1;
        if (base + 1 < N_NODES) d1 = deg[base + 1] + 1;
        if (base + 2 < N_NODES) d2 = deg[base + 2] + 1;
        if (base + 3 < N_NODES) d3 = deg[base + 3] + 1;
    }
    const int s0 = d0, s1 = s0 + d1, s2 = s1 + d2, s3 = s2 + d3;
    int inc = s3;                            // wave-inclusive scan of totals
    #pragma unroll
    for (int off = 1; off < 64; off <<= 1) {
        const int t = __shfl_up(inc, off);
        if (lane >= off) inc += t;
    }
    if (lane == 63) wsum[wv] = inc;
    __syncthreads();
    int wbase = 0;
    for (int k = 0; k < wv; ++k) wbase += wsum[k];
    const int tb = wbase + inc - s3;         // exclusive base for this thread
    if (base + 3 < N_NODES) {
        *(int4*)&partial[base] = (int4){tb, tb + s0, tb + s1, tb + s2};
    } else {
        if (base + 0 < N_NODES) partial[base + 0] = tb;
        if (base + 1 < N_NODES) partial[base + 1] = tb + s0;
        if (base + 2 < N_NODES) partial[base + 2] = tb + s1;
        if (base + 3 < N_NODES) partial[base + 3] = tb + s2;
    }
    if (tid == 255) bsum[blockIdx.x] = wbase + inc;
}

// ---- K3: scatter edges + finalize row_start (bsum scan per block) ----

__global__ __launch_bounds__(256) void scatter_fin(
    const int* __restrict__ esrc, const int* __restrict__ edst,
    const int* __restrict__ partial, const int* __restrict__ bsum,
    const unsigned short* __restrict__ ppos,
    int* __restrict__ row_st, unsigned short* __restrict__ csr_src)
{
    __shared__ int sb[64];
    if (threadIdx.x < 64) {                  // wave 0: exclusive scan of bsum
        const int v = (threadIdx.x < SCAN_BLOCKS) ? bsum[threadIdx.x] : 0;
        int s = v;
        #pragma unroll
        for (int off = 1; off < 64; off <<= 1) {
            const int t = __shfl_up(s, off);
            if ((int)threadIdx.x >= off) s += t;
        }
        sb[threadIdx.x] = s - v;
    }
    __syncthreads();
    const int idx = blockIdx.x * 256 + threadIdx.x;
    if (idx < N_EDGES) {
        const int d = edst[idx];
        csr_src[partial[d] + sb[d >> 10] + 1 + ppos[idx]] = (unsigned short)esrc[idx];
    } else if (idx < E_TOT) {
        const int i = idx - N_EDGES;                 // node domain
        const int r = partial[i] + sb[i >> 10];
        row_st[i] = r;
        csr_src[r] = (unsigned short)i;              // self loop in slot 0
        if (i == 0) row_st[N_NODES] = E_TOT;
    }
}

// ---- K4: aggregation — wave/node, 4 edges in flight + prefetch ----

__global__ __launch_bounds__(256) void gat_agg(
    const int* __restrict__ row_start, const unsigned short* __restrict__ csr_src,
    const unsigned short* __restrict__ hb, const float* __restrict__ a_src,
    const float* __restrict__ a_dst, const float* __restrict__ bias,
    float* __restrict__ out)
{
    __shared__ float ws[4][256];             // [wave][edge*4 + head]
    const int wv = threadIdx.x >> 6;
    const int node = blockIdx.x * 4 + wv;
    if (node >= N_NODES) return;
    const int lane = threadIdx.x & 63;
    const int q    = lane >> 4;              // quarter: which edge of the 4
    const int li   = lane & 15;
    const int ch0  = li * 8;                 // 8 channels per lane
    const int hd   = li >> 2;                // head of my channels (ch0/32)
    const float4 ad4 = *(const float4*)&a_dst[node * 4];
    const int p0 = row_start[node], p1 = row_start[node + 1];

    float acc[8] = {0.f,0.f,0.f,0.f,0.f,0.f,0.f,0.f};
    float dsum = 0.f;

    for (int base = p0; base < p1; base += 64) {
        int m = p1 - base; if (m > 64) m = 64;
        int sv = 0;
        if (lane < m) {
            sv = (int)csr_src[base + lane];  // coalesced batch of src ids
            const float4 av = *(const float4*)&a_src[sv * 4];
            float t; float4 w4;
            t = av.x + ad4.x; t = t > 0.f ? t : NEG_SLOPE * t; w4.x = __expf(t);
            t = av.y + ad4.y; t = t > 0.f ? t : NEG_SLOPE * t; w4.y = __expf(t);
            t = av.z + ad4.z; t = t > 0.f ? t : NEG_SLOPE * t; w4.z = __expf(t);
            t = av.w + ad4.w; t = t > 0.f ? t : NEG_SLOPE * t; w4.w = __expf(t);
            *(float4*)&ws[wv][lane * 4] = w4; // all 4 head weights for my edge
        }
        // software-pipelined: prefetch next 4-edge group's h rows while
        // accumulating the current group (8 rows in flight per wave).
        const int i0 = (q < m) ? q : 0;
        int s_cur = __shfl(sv, i0);
        uint4 hv = *(const uint4*)&hb[(size_t)s_cur * 128 + ch0];
        for (int j = 0; j < m; j += 4) {
            const int ei  = j + q;
            const int idx = ei < m ? ei : j;     // edge whose row is in hv
            const int ein = ei + 4;
            const int idxn = ein < m ? ein : 0;  // next group's edge (clamped)
            const int s_nxt = __shfl(sv, idxn);
            const uint4 hvn = *(const uint4*)&hb[(size_t)s_nxt * 128 + ch0];
            float w = ws[wv][idx * 4 + hd];
            if (ei >= m) w = 0.f;
            acc[0] += w * __uint_as_float(hv.x << 16);
            acc[1] += w * __uint_as_float(hv.x & 0xFFFF0000u);
            acc[2] += w * __uint_as_float(hv.y << 16);
            acc[3] += w * __uint_as_float(hv.y & 0xFFFF0000u);
            acc[4] += w * __uint_as_float(hv.z << 16);
            acc[5] += w * __uint_as_float(hv.z & 0xFFFF0000u);
            acc[6] += w * __uint_as_float(hv.w << 16);
            acc[7] += w * __uint_as_float(hv.w & 0xFFFF0000u);
            dsum += w;
            hv = hvn;
        }
    }
    // combine the four quarters (disjoint edge subsets, same channels)
    #pragma unroll
    for (int off = 16; off <= 32; off <<= 1) {
        #pragma unroll
        for (int r = 0; r < 8; ++r) acc[r] += __shfl_xor(acc[r], off);
        dsum += __shfl_xor(dsum, off);
    }
    if (q == 0) {
        const float inv = 1.f / dsum;        // dsum >= exp(self) > 0
        const float4 b0 = *(const float4*)&bias[ch0];
        const float4 b1 = *(const float4*)&bias[ch0 + 4];
        float4 o0, o1;
        o0.x = acc[0]*inv + b0.x; o0.y = acc[1]*inv + b0.y;
        o0.z = acc[2]*inv + b0.z; o0.w = acc[3]*inv + b0.w;
        o1.x = acc[4]*inv + b1.x; o1.y = acc[5]*inv + b1.y;
        o1.z = acc[6]*inv + b1.z; o1.w = acc[7]*inv + b1.w;
        *(float4*)&out[(size_t)node * HC + ch0]     = o0;
        *(float4*)&out[(size_t)node * HC + ch0 + 4] = o1;
    }
}

extern "C" void kernel_launch(void* const* d_in, const int* in_sizes, int n_in,
                              void* d_out, int out_size, void* d_ws, size_t ws_size,
                              hipStream_t stream) {
    const float* x       = (const float*)d_in[0];
    const int*   ei      = (const int*)  d_in[1];   // [2,E]: row0=src, row1=dst
    const float* W       = (const float*)d_in[2];
    const float* att_src = (const float*)d_in[3];
    const float* att_dst = (const float*)d_in[4];
    const float* bias    = (const float*)d_in[5];
    float* out = (float*)d_out;

    // ws layout (~18 MB): hb | a_src | a_dst | csr(u16) | ppos(u16) | partial | row_st | deg | bsum
    char* p = (char*)d_ws;
    unsigned short* hb  = (unsigned short*)p; p += (size_t)N_NODES * HC * 2;  // 12.8 MB
    float* a_src = (float*)p; p += (size_t)N_NODES * 4 * 4;                   // 800 KB
    float* a_dst = (float*)p; p += (size_t)N_NODES * 4 * 4;
    unsigned short* csr_src = (unsigned short*)p; p += (size_t)E_TOT * 2;     // 1.7 MB
    unsigned short* ppos    = (unsigned short*)p; p += (size_t)N_EDGES * 2;   // 1.6 MB
    int* partial = (int*)p;   p += N_NODES * 4;
    int* row_st  = (int*)p;   p += (N_NODES + 4) * 4;
    int* deg     = (int*)p;   p += N_NODES * 4;
    int* bsum    = (int*)p;

    const int* esrc = ei;
    const int* edst = ei + N_EDGES;

    hipMemsetAsync(deg, 0, (size_t)N_NODES * sizeof(int), stream);

    gemm_hist  <<<NB_GEMM + NB_HIST, 256, 0, stream>>>(x, W, att_src, att_dst,
                                                       edst, hb, a_src, a_dst, deg, ppos);
    scan       <<<SCAN_BLOCKS, 256, 0, stream>>>(deg, partial, bsum);
    scatter_fin<<<(E_TOT + 255) / 256, 256, 0, stream>>>(esrc, edst, partial, bsum,
                                                         ppos, row_st, csr_src);
    gat_agg    <<<(N_NODES + 3) / 4, 256, 0, stream>>>(row_st, csr_src, hb, a_src,
                                                       a_dst, bias, out);
}